// Round 14
// baseline (232.840 us; speedup 1.0000x reference)
//
#include <hip/hip_runtime.h>
#include <hip/hip_fp16.h>
#include <math.h>

// PhysicsResidual via 2nd-order forward-mode AD, split-fp16 MFMA, operand-swapped.
// State per point: 6 vectors of 128 (h, 4 first derivs, q = signed 2nd-deriv combo).
// R14 = R13 (P=8, 5-6 blocks/CU, interleaved col = 2p + (v&1)) with the rule #20
// scratch bug fixed: the epilogue write-back no longer selects a POINTER to the
// per-nt output arrays (that forced o0/o1/o2 to scratch: WRITE_SIZE 21MB, VGPR 48).
// Macro-expanded per-nt blocks keep every access compile-time-constant.
// Per layer GEMM: A = W (M=128), B = X^T (N = 48 = 6v x 8p), K = 128.
// Wave wn owns m-tiles {2wn, 2wn+1} x all 3 n-tiles (acc = 6 f32x4 = 24 VGPR).
// Epilogue: even lane holds (z,d1,d3), odd (d0,d2,q); 3x shfl_xor(1) even->odd.
// Tripwires: WRITE_SIZE ~0.26MB, VGPR 80-100, Occupancy ~50.

typedef _Float16 f16x8 __attribute__((ext_vector_type(8)));
typedef _Float16 f16x4 __attribute__((ext_vector_type(4)));
typedef _Float16 f16x2 __attribute__((ext_vector_type(2)));
typedef float    f32x4 __attribute__((ext_vector_type(4)));

constexpr int TPB  = 256;
constexpr int P    = 8;     // points per block
constexpr int H    = 128;
constexpr int NV   = 6;
constexpr int NT   = 3;     // n-tiles (16 cols each: 2 v x 8 p)
constexpr int XFRAG_HALVES = NT * 4 * 64 * 8;   // 6144 halves = 12288 B per plane
// pre-split W plane: 5 layers x 8 mt x 4 ks x 64 lanes x 8 halves
constexpr int WFRAG_HALVES = 5 * 8 * 4 * 64 * 8;           // 81920 halves
constexpr size_t WS_NEEDED = 2 * WFRAG_HALVES * sizeof(_Float16); // 327680 B

__device__ __forceinline__ float fast_tanh(float v) {
    float e = __expf(-2.0f * fabsf(v));
    float r = __builtin_amdgcn_rcpf(1.0f + e);
    return copysignf((1.0f - e) * r, v);
}

__device__ __forceinline__ f16x2 pkrtz(float a, float b) {
    return __builtin_bit_cast(f16x2, __builtin_amdgcn_cvt_pkrtz(a, b));
}

// ---------------- pre-split kernel: W1..W5 -> fp16 hi/lo fragments -----------
__global__ __launch_bounds__(256) void presplit_w(
    const float* __restrict__ W1, const float* __restrict__ W2,
    const float* __restrict__ W3, const float* __restrict__ W4,
    const float* __restrict__ W5, _Float16* __restrict__ whi,
    _Float16* __restrict__ wlo)
{
    const int gid = blockIdx.x * 256 + threadIdx.x;   // 0..10239
    const float* Ws[5] = { W1, W2, W3, W4, W5 };
    const int lane = gid & 63;
    const int rest = gid >> 6;        // 0..159
    const int ks   = rest & 3;
    const int mt   = (rest >> 2) & 7;
    const int l    = rest >> 5;       // 0..4
    const int n    = mt * 16 + (lane & 15);
    const int k0   = ks * 32 + (lane >> 4) * 8;
    const float4 u0 = *(const float4*)&Ws[l][n * H + k0];
    const float4 u1 = *(const float4*)&Ws[l][n * H + k0 + 4];
    const float vv[8] = { u0.x, u0.y, u0.z, u0.w, u1.x, u1.y, u1.z, u1.w };
    f16x8 h, o;
    #pragma unroll
    for (int e = 0; e < 8; ++e) {
        _Float16 hh = (_Float16)vv[e];
        h[e] = hh;
        o[e] = (_Float16)(vv[e] - (float)hh);
    }
    *(f16x8*)&whi[gid * 8] = h;
    *(f16x8*)&wlo[gid * 8] = o;
}

// ---------------- main kernel ------------------------------------------------
__global__ __launch_bounds__(TPB, 5) void pinn_mfma11(
    const float* __restrict__ t, const float* __restrict__ x,
    const float* __restrict__ y, const float* __restrict__ z,
    const float* __restrict__ W0, const float* __restrict__ b0,
    const float* __restrict__ W1, const float* __restrict__ b1,
    const float* __restrict__ W2, const float* __restrict__ b2,
    const float* __restrict__ W3, const float* __restrict__ b3,
    const float* __restrict__ W4, const float* __restrict__ b4,
    const float* __restrict__ W5, const float* __restrict__ b5,
    const float* __restrict__ W6,
    const _Float16* __restrict__ whi, const _Float16* __restrict__ wlo,
    int use_pre, float* __restrict__ out, int N)
{
    __shared__ _Float16 sXhi[XFRAG_HALVES];    // 12288 B
    __shared__ _Float16 sXlo[XFRAG_HALVES];    // 12288 B
    __shared__ float    sRed[4][P];            // 128 B -> ~24.8 KB total

    const int tid  = threadIdx.x;
    const int lane = tid & 63;
    const int wn   = tid >> 6;     // wave 0..3: owns m-tiles {2wn, 2wn+1}
    const int l15  = lane & 15;
    const int l4   = lane >> 4;    // 0..3
    const int vo   = lane & 1;     // v-parity this lane's column holds
    const int gb   = blockIdx.x * P;

    // ---------------- layer 0 (input dim 4, analytic tangents) -------------
    {
        const int p0 = tid >> 5;          // 0..7
        const int i0 = tid & 31;          // owns neurons i0*4 .. i0*4+3
        int gp = gb + p0; if (gp >= N) gp = N - 1;
        const float pt0 = t[gp], pt1 = x[gp], pt2 = y[gp], pt3 = z[gp];
        float nv[NV][4];
        #pragma unroll
        for (int j = 0; j < 4; ++j) {
            const int i = i0 * 4 + j;
            const float4 wv = *(const float4*)&W0[i * 4];
            const float zv = fmaf(wv.x, pt0, fmaf(wv.y, pt1, fmaf(wv.z, pt2, fmaf(wv.w, pt3, b0[i]))));
            const float hv = fast_tanh(zv);
            const float s  = 1.0f - hv * hv;
            const float ssq = ((wv.x * wv.x - wv.y * wv.y) - wv.z * wv.z) - wv.w * wv.w;
            nv[0][j] = hv;       nv[1][j] = s * wv.x; nv[2][j] = s * wv.y;
            nv[3][j] = s * wv.z; nv[4][j] = s * wv.w; nv[5][j] = -2.0f * hv * s * ssq;
        }
        // frag-major interleaved: [v][p][k=i0*4+j] -> frag(nt=v>>1, ks=i0>>3),
        // lane = 16*((i0>>1)&3) + 2*p0 + (v&1), e = (i0&1)*4 + j
        #pragma unroll
        for (int v = 0; v < NV; ++v) {
            f16x4 hh, oo;
            #pragma unroll
            for (int j = 0; j < 4; ++j) {
                _Float16 h_ = (_Float16)nv[v][j];
                hh[j] = h_;
                oo[j] = (_Float16)(nv[v][j] - (float)h_);
            }
            const int off = (((v >> 1) * 4 + (i0 >> 3)) * 64
                             + 16 * ((i0 >> 1) & 3) + 2 * p0 + (v & 1)) * 8
                            + (i0 & 1) * 4;
            *(f16x4*)&sXhi[off] = hh;
            *(f16x4*)&sXlo[off] = oo;
        }
    }
    __syncthreads();

    for (int l = 0; l < 5; ++l) {
        f32x4 acc[NT][2];
        #pragma unroll
        for (int nt = 0; nt < NT; ++nt)
            #pragma unroll
            for (int m = 0; m < 2; ++m) acc[nt][m] = (f32x4){0.f, 0.f, 0.f, 0.f};

        const float* __restrict__ Wc =
            (l == 0) ? W1 : (l == 1) ? W2 : (l == 2) ? W3 : (l == 3) ? W4 : W5;

        #pragma unroll
        for (int ks = 0; ks < 4; ++ks) {
            // A frags (W hi/lo) for wave's 2 m-tiles, this ks
            f16x8 ah[2], al[2];
            if (use_pre) {
                #pragma unroll
                for (int m = 0; m < 2; ++m) {
                    const int f = ((l * 8 + (wn * 2 + m)) * 4 + ks) * 64 + lane;
                    ah[m] = *(const f16x8*)&whi[f * 8];
                    al[m] = *(const f16x8*)&wlo[f * 8];
                }
            } else {
                #pragma unroll
                for (int m = 0; m < 2; ++m) {
                    const int n  = (wn * 2 + m) * 16 + l15;
                    const int k0 = ks * 32 + l4 * 8;
                    const float4 u0 = *(const float4*)&Wc[n * H + k0];
                    const float4 u1 = *(const float4*)&Wc[n * H + k0 + 4];
                    const float vv[8] = { u0.x, u0.y, u0.z, u0.w, u1.x, u1.y, u1.z, u1.w };
                    #pragma unroll
                    for (int e = 0; e < 8; ++e) {
                        _Float16 h_ = (_Float16)vv[e];
                        ah[m][e] = h_;
                        al[m][e] = (_Float16)(vv[e] - (float)h_);
                    }
                }
            }
            // B frags: lane-contiguous 16B (conflict-free)
            f16x8 xh[NT], xl[NT];
            #pragma unroll
            for (int nt = 0; nt < NT; ++nt) {
                const int base = ((nt * 4 + ks) * 64 + lane) * 8;
                xh[nt] = *(const f16x8*)&sXhi[base];
                xl[nt] = *(const f16x8*)&sXlo[base];
            }
            __builtin_amdgcn_s_setprio(1);
            #pragma unroll
            for (int nt = 0; nt < NT; ++nt)
                #pragma unroll
                for (int m = 0; m < 2; ++m)
                    acc[nt][m] = __builtin_amdgcn_mfma_f32_16x16x32_f16(ah[m], xh[nt], acc[nt][m], 0, 0, 0);
            #pragma unroll
            for (int nt = 0; nt < NT; ++nt)
                #pragma unroll
                for (int m = 0; m < 2; ++m)
                    acc[nt][m] = __builtin_amdgcn_mfma_f32_16x16x32_f16(ah[m], xl[nt], acc[nt][m], 0, 0, 0);
            #pragma unroll
            for (int nt = 0; nt < NT; ++nt)
                #pragma unroll
                for (int m = 0; m < 2; ++m)
                    acc[nt][m] = __builtin_amdgcn_mfma_f32_16x16x32_f16(al[m], xh[nt], acc[nt][m], 0, 0, 0);
            __builtin_amdgcn_s_setprio(0);
        }
        __syncthreads();   // all GEMM reads of sX done before overwrite

        // D layout per acc tile: col = l15 -> (p = l15>>1, v-parity = l15&1),
        // row (neuron-in-mt) = l4*4 + r. even lane holds (z,d1,d3); odd (d0,d2,q).
        if (l < 4) {
            const float* __restrict__ bc =
                (l == 0) ? b1 : (l == 1) ? b2 : (l == 2) ? b3 : b4;
            #pragma unroll
            for (int m = 0; m < 2; ++m) {
                float o0[4], o1[4], o2[4];   // per-r outputs, nt = 0,1,2
                #pragma unroll
                for (int r = 0; r < 4; ++r) {
                    const int n  = (wn * 2 + m) * 16 + l4 * 4 + r;
                    const float a0 = acc[0][m][r];   // even: z   | odd: d0
                    const float a1 = acc[1][m][r];   // even: d1  | odd: d2
                    const float a2 = acc[2][m][r];   // even: d3  | odd: q
                    // even-lane math (odd computes harmless garbage)
                    const float hv  = fast_tanh(a0 + bc[n]);
                    const float s   = 1.0f - hv * hv;
                    const float ue  = a1 * a1 + a2 * a2;     // d1^2 + d3^2
                    const float hs2 = 2.0f * hv * s;
                    // pass even-lane quantities to the odd lane
                    const float s_x   = __shfl_xor(s, 1, 64);
                    const float hs2_x = __shfl_xor(hs2, 1, 64);
                    const float ue_x  = __shfl_xor(ue, 1, 64);
                    // odd-lane math
                    const float uo  = a0 * a0 - a1 * a1;     // d0^2 - d2^2
                    const float ssq = uo - ue_x;
                    const float qn  = fmaf(s_x, a2, -hs2_x * ssq);
                    // outputs: even {h, s*d1, s*d3}; odd {s*d0, s*d2, qn}
                    o0[r] = vo ? s_x * a0 : hv;
                    o1[r] = vo ? s_x * a1 : s * a1;
                    o2[r] = vo ? qn       : s * a2;
                }
                // write back: frag(nt, ks'=wn), lane' = 16*(2m + (l4>>1)) + l15,
                // e0 = (l4&1)*4  (k = n). MACRO expansion: every index is a
                // compile-time constant -> no scratch (R13's pointer-select bug).
                const int wbase = 16 * (2 * m + (l4 >> 1)) + l15;
                const int e0    = (l4 & 1) * 4;
#define WRITE_NT(NTI, OV)                                                      \
                {                                                              \
                    const f16x2 h01 = pkrtz(OV[0], OV[1]);                     \
                    const f16x2 h23 = pkrtz(OV[2], OV[3]);                     \
                    const float q0 = OV[0] - (float)h01[0];                    \
                    const float q1 = OV[1] - (float)h01[1];                    \
                    const float q2 = OV[2] - (float)h23[0];                    \
                    const float q3 = OV[3] - (float)h23[1];                    \
                    const f16x2 g01 = pkrtz(q0, q1);                           \
                    const f16x2 g23 = pkrtz(q2, q3);                           \
                    const int off = (((NTI) * 4 + wn) * 64 + wbase) * 8 + e0;  \
                    *(f16x4*)&sXhi[off] =                                      \
                        __builtin_shufflevector(h01, h23, 0, 1, 2, 3);         \
                    *(f16x4*)&sXlo[off] =                                      \
                        __builtin_shufflevector(g01, g23, 0, 1, 2, 3);         \
                }
                WRITE_NT(0, o0)
                WRITE_NT(1, o1)
                WRITE_NT(2, o2)
#undef WRITE_NT
            }
            __syncthreads();
        } else {
            // last tanh layer + head: res = sum_n W6[n] * q_final[n]  (odd lanes)
            float part = 0.0f;
            #pragma unroll
            for (int m = 0; m < 2; ++m) {
                #pragma unroll
                for (int r = 0; r < 4; ++r) {
                    const int n  = (wn * 2 + m) * 16 + l4 * 4 + r;
                    const float a0 = acc[0][m][r];
                    const float a1 = acc[1][m][r];
                    const float a2 = acc[2][m][r];
                    const float hv  = fast_tanh(a0 + b5[n]);
                    const float s   = 1.0f - hv * hv;
                    const float ue  = a1 * a1 + a2 * a2;
                    const float hs2 = 2.0f * hv * s;
                    const float s_x   = __shfl_xor(s, 1, 64);
                    const float hs2_x = __shfl_xor(hs2, 1, 64);
                    const float ue_x  = __shfl_xor(ue, 1, 64);
                    const float uo  = a0 * a0 - a1 * a1;
                    const float ssq = uo - ue_x;
                    const float qf  = fmaf(s_x, a2, -hs2_x * ssq);
                    part = fmaf(W6[n], qf, part);   // only odd lanes' qf is real
                }
            }
            part += __shfl_xor(part, 16, 64);
            part += __shfl_xor(part, 32, 64);
            if (lane < 16 && (lane & 1)) sRed[wn][lane >> 1] = part;
        }
    }

    __syncthreads();
    if (tid < P) {
        const float rsum = sRed[0][tid] + sRed[1][tid] + sRed[2][tid] + sRed[3][tid];
        const int o = gb + tid;
        if (o < N) out[o] = rsum;
    }
}

extern "C" void kernel_launch(void* const* d_in, const int* in_sizes, int n_in,
                              void* d_out, int out_size, void* d_ws, size_t ws_size,
                              hipStream_t stream) {
    const float* t  = (const float*)d_in[0];
    const float* x  = (const float*)d_in[1];
    const float* y  = (const float*)d_in[2];
    const float* z  = (const float*)d_in[3];
    const float* W0 = (const float*)d_in[4];
    const float* b0 = (const float*)d_in[5];
    const float* W1 = (const float*)d_in[6];
    const float* b1 = (const float*)d_in[7];
    const float* W2 = (const float*)d_in[8];
    const float* b2 = (const float*)d_in[9];
    const float* W3 = (const float*)d_in[10];
    const float* b3 = (const float*)d_in[11];
    const float* W4 = (const float*)d_in[12];
    const float* b4 = (const float*)d_in[13];
    const float* W5 = (const float*)d_in[14];
    const float* b5 = (const float*)d_in[15];
    const float* W6 = (const float*)d_in[16];
    // d_in[17] = b6: unused (drops out of all derivatives)

    const int N = in_sizes[0];
    float* out = (float*)d_out;

    const int use_pre = (ws_size >= WS_NEEDED) ? 1 : 0;
    _Float16* whi = (_Float16*)d_ws;
    _Float16* wlo = whi + WFRAG_HALVES;

    if (use_pre) {
        presplit_w<<<(5 * 8 * 4 * 64) / 256, 256, 0, stream>>>(W1, W2, W3, W4, W5, whi, wlo);
    }
    const int grid = (N + P - 1) / P;
    pinn_mfma11<<<grid, TPB, 0, stream>>>(
        t, x, y, z, W0, b0, W1, b1, W2, b2, W3, b3, W4, b4, W5, b5, W6,
        whi, wlo, use_pre, out, N);
}

// Round 15
// 215.700 us; speedup vs baseline: 1.0795x; 1.0795x over previous
//
#include <hip/hip_runtime.h>
#include <hip/hip_fp16.h>
#include <math.h>

// PhysicsResidual via 2nd-order forward-mode AD, split-fp16 MFMA, operand-swapped.
// State per point: 6 vectors of 128 (h, 4 first derivs, q = signed 2nd-deriv combo).
// R15 = R14 (P=8, interleaved col = 2p + (v&1), macro-expanded epilogue writes)
// with __launch_bounds__(256,4): R13/R14's (256,5) capped VGPR at ~102 < the
// ~110-125 the kernel needs -> allocator spill cascade (VGPR 48, WRITE 21->71MB).
// Cap 128 fits; 4 blocks/CU (16 waves) vs 3 blocks at P=16 -> occupancy lever,
// now without scratch.
// Per layer GEMM: A = W (M=128), B = X^T (N = 48 = 6v x 8p), K = 128.
// Wave wn owns m-tiles {2wn, 2wn+1} x all 3 n-tiles (acc = 6 f32x4 = 24 VGPR).
// Epilogue: even lane holds (z,d1,d3), odd (d0,d2,q); 3x shfl_xor(1) even->odd.
// Tripwires: WRITE_SIZE ~0.26MB, VGPR 100-126, Occupancy ~50.

typedef _Float16 f16x8 __attribute__((ext_vector_type(8)));
typedef _Float16 f16x4 __attribute__((ext_vector_type(4)));
typedef _Float16 f16x2 __attribute__((ext_vector_type(2)));
typedef float    f32x4 __attribute__((ext_vector_type(4)));

constexpr int TPB  = 256;
constexpr int P    = 8;     // points per block
constexpr int H    = 128;
constexpr int NV   = 6;
constexpr int NT   = 3;     // n-tiles (16 cols each: 2 v x 8 p)
constexpr int XFRAG_HALVES = NT * 4 * 64 * 8;   // 6144 halves = 12288 B per plane
// pre-split W plane: 5 layers x 8 mt x 4 ks x 64 lanes x 8 halves
constexpr int WFRAG_HALVES = 5 * 8 * 4 * 64 * 8;           // 81920 halves
constexpr size_t WS_NEEDED = 2 * WFRAG_HALVES * sizeof(_Float16); // 327680 B

__device__ __forceinline__ float fast_tanh(float v) {
    float e = __expf(-2.0f * fabsf(v));
    float r = __builtin_amdgcn_rcpf(1.0f + e);
    return copysignf((1.0f - e) * r, v);
}

__device__ __forceinline__ f16x2 pkrtz(float a, float b) {
    return __builtin_bit_cast(f16x2, __builtin_amdgcn_cvt_pkrtz(a, b));
}

// ---------------- pre-split kernel: W1..W5 -> fp16 hi/lo fragments -----------
__global__ __launch_bounds__(256) void presplit_w(
    const float* __restrict__ W1, const float* __restrict__ W2,
    const float* __restrict__ W3, const float* __restrict__ W4,
    const float* __restrict__ W5, _Float16* __restrict__ whi,
    _Float16* __restrict__ wlo)
{
    const int gid = blockIdx.x * 256 + threadIdx.x;   // 0..10239
    const float* Ws[5] = { W1, W2, W3, W4, W5 };
    const int lane = gid & 63;
    const int rest = gid >> 6;        // 0..159
    const int ks   = rest & 3;
    const int mt   = (rest >> 2) & 7;
    const int l    = rest >> 5;       // 0..4
    const int n    = mt * 16 + (lane & 15);
    const int k0   = ks * 32 + (lane >> 4) * 8;
    const float4 u0 = *(const float4*)&Ws[l][n * H + k0];
    const float4 u1 = *(const float4*)&Ws[l][n * H + k0 + 4];
    const float vv[8] = { u0.x, u0.y, u0.z, u0.w, u1.x, u1.y, u1.z, u1.w };
    f16x8 h, o;
    #pragma unroll
    for (int e = 0; e < 8; ++e) {
        _Float16 hh = (_Float16)vv[e];
        h[e] = hh;
        o[e] = (_Float16)(vv[e] - (float)hh);
    }
    *(f16x8*)&whi[gid * 8] = h;
    *(f16x8*)&wlo[gid * 8] = o;
}

// ---------------- main kernel ------------------------------------------------
__global__ __launch_bounds__(TPB, 4) void pinn_mfma12(
    const float* __restrict__ t, const float* __restrict__ x,
    const float* __restrict__ y, const float* __restrict__ z,
    const float* __restrict__ W0, const float* __restrict__ b0,
    const float* __restrict__ W1, const float* __restrict__ b1,
    const float* __restrict__ W2, const float* __restrict__ b2,
    const float* __restrict__ W3, const float* __restrict__ b3,
    const float* __restrict__ W4, const float* __restrict__ b4,
    const float* __restrict__ W5, const float* __restrict__ b5,
    const float* __restrict__ W6,
    const _Float16* __restrict__ whi, const _Float16* __restrict__ wlo,
    int use_pre, float* __restrict__ out, int N)
{
    __shared__ _Float16 sXhi[XFRAG_HALVES];    // 12288 B
    __shared__ _Float16 sXlo[XFRAG_HALVES];    // 12288 B
    __shared__ float    sRed[4][P];            // 128 B -> ~24.8 KB total

    const int tid  = threadIdx.x;
    const int lane = tid & 63;
    const int wn   = tid >> 6;     // wave 0..3: owns m-tiles {2wn, 2wn+1}
    const int l15  = lane & 15;
    const int l4   = lane >> 4;    // 0..3
    const int vo   = lane & 1;     // v-parity this lane's column holds
    const int gb   = blockIdx.x * P;

    // ---------------- layer 0 (input dim 4, analytic tangents) -------------
    {
        const int p0 = tid >> 5;          // 0..7
        const int i0 = tid & 31;          // owns neurons i0*4 .. i0*4+3
        int gp = gb + p0; if (gp >= N) gp = N - 1;
        const float pt0 = t[gp], pt1 = x[gp], pt2 = y[gp], pt3 = z[gp];
        float nv[NV][4];
        #pragma unroll
        for (int j = 0; j < 4; ++j) {
            const int i = i0 * 4 + j;
            const float4 wv = *(const float4*)&W0[i * 4];
            const float zv = fmaf(wv.x, pt0, fmaf(wv.y, pt1, fmaf(wv.z, pt2, fmaf(wv.w, pt3, b0[i]))));
            const float hv = fast_tanh(zv);
            const float s  = 1.0f - hv * hv;
            const float ssq = ((wv.x * wv.x - wv.y * wv.y) - wv.z * wv.z) - wv.w * wv.w;
            nv[0][j] = hv;       nv[1][j] = s * wv.x; nv[2][j] = s * wv.y;
            nv[3][j] = s * wv.z; nv[4][j] = s * wv.w; nv[5][j] = -2.0f * hv * s * ssq;
        }
        // frag-major interleaved: [v][p][k=i0*4+j] -> frag(nt=v>>1, ks=i0>>3),
        // lane = 16*((i0>>1)&3) + 2*p0 + (v&1), e = (i0&1)*4 + j
        #pragma unroll
        for (int v = 0; v < NV; ++v) {
            f16x4 hh, oo;
            #pragma unroll
            for (int j = 0; j < 4; ++j) {
                _Float16 h_ = (_Float16)nv[v][j];
                hh[j] = h_;
                oo[j] = (_Float16)(nv[v][j] - (float)h_);
            }
            const int off = (((v >> 1) * 4 + (i0 >> 3)) * 64
                             + 16 * ((i0 >> 1) & 3) + 2 * p0 + (v & 1)) * 8
                            + (i0 & 1) * 4;
            *(f16x4*)&sXhi[off] = hh;
            *(f16x4*)&sXlo[off] = oo;
        }
    }
    __syncthreads();

    for (int l = 0; l < 5; ++l) {
        f32x4 acc[NT][2];
        #pragma unroll
        for (int nt = 0; nt < NT; ++nt)
            #pragma unroll
            for (int m = 0; m < 2; ++m) acc[nt][m] = (f32x4){0.f, 0.f, 0.f, 0.f};

        const float* __restrict__ Wc =
            (l == 0) ? W1 : (l == 1) ? W2 : (l == 2) ? W3 : (l == 3) ? W4 : W5;

        #pragma unroll
        for (int ks = 0; ks < 4; ++ks) {
            // A frags (W hi/lo) for wave's 2 m-tiles, this ks
            f16x8 ah[2], al[2];
            if (use_pre) {
                #pragma unroll
                for (int m = 0; m < 2; ++m) {
                    const int f = ((l * 8 + (wn * 2 + m)) * 4 + ks) * 64 + lane;
                    ah[m] = *(const f16x8*)&whi[f * 8];
                    al[m] = *(const f16x8*)&wlo[f * 8];
                }
            } else {
                #pragma unroll
                for (int m = 0; m < 2; ++m) {
                    const int n  = (wn * 2 + m) * 16 + l15;
                    const int k0 = ks * 32 + l4 * 8;
                    const float4 u0 = *(const float4*)&Wc[n * H + k0];
                    const float4 u1 = *(const float4*)&Wc[n * H + k0 + 4];
                    const float vv[8] = { u0.x, u0.y, u0.z, u0.w, u1.x, u1.y, u1.z, u1.w };
                    #pragma unroll
                    for (int e = 0; e < 8; ++e) {
                        _Float16 h_ = (_Float16)vv[e];
                        ah[m][e] = h_;
                        al[m][e] = (_Float16)(vv[e] - (float)h_);
                    }
                }
            }
            // B frags: lane-contiguous 16B (conflict-free)
            f16x8 xh[NT], xl[NT];
            #pragma unroll
            for (int nt = 0; nt < NT; ++nt) {
                const int base = ((nt * 4 + ks) * 64 + lane) * 8;
                xh[nt] = *(const f16x8*)&sXhi[base];
                xl[nt] = *(const f16x8*)&sXlo[base];
            }
            __builtin_amdgcn_s_setprio(1);
            #pragma unroll
            for (int nt = 0; nt < NT; ++nt)
                #pragma unroll
                for (int m = 0; m < 2; ++m)
                    acc[nt][m] = __builtin_amdgcn_mfma_f32_16x16x32_f16(ah[m], xh[nt], acc[nt][m], 0, 0, 0);
            #pragma unroll
            for (int nt = 0; nt < NT; ++nt)
                #pragma unroll
                for (int m = 0; m < 2; ++m)
                    acc[nt][m] = __builtin_amdgcn_mfma_f32_16x16x32_f16(ah[m], xl[nt], acc[nt][m], 0, 0, 0);
            #pragma unroll
            for (int nt = 0; nt < NT; ++nt)
                #pragma unroll
                for (int m = 0; m < 2; ++m)
                    acc[nt][m] = __builtin_amdgcn_mfma_f32_16x16x32_f16(al[m], xh[nt], acc[nt][m], 0, 0, 0);
            __builtin_amdgcn_s_setprio(0);
        }
        __syncthreads();   // all GEMM reads of sX done before overwrite

        // D layout per acc tile: col = l15 -> (p = l15>>1, v-parity = l15&1),
        // row (neuron-in-mt) = l4*4 + r. even lane holds (z,d1,d3); odd (d0,d2,q).
        if (l < 4) {
            const float* __restrict__ bc =
                (l == 0) ? b1 : (l == 1) ? b2 : (l == 2) ? b3 : b4;
            #pragma unroll
            for (int m = 0; m < 2; ++m) {
                float o0[4], o1[4], o2[4];   // per-r outputs, nt = 0,1,2
                #pragma unroll
                for (int r = 0; r < 4; ++r) {
                    const int n  = (wn * 2 + m) * 16 + l4 * 4 + r;
                    const float a0 = acc[0][m][r];   // even: z   | odd: d0
                    const float a1 = acc[1][m][r];   // even: d1  | odd: d2
                    const float a2 = acc[2][m][r];   // even: d3  | odd: q
                    // even-lane math (odd computes harmless garbage)
                    const float hv  = fast_tanh(a0 + bc[n]);
                    const float s   = 1.0f - hv * hv;
                    const float ue  = a1 * a1 + a2 * a2;     // d1^2 + d3^2
                    const float hs2 = 2.0f * hv * s;
                    // pass even-lane quantities to the odd lane
                    const float s_x   = __shfl_xor(s, 1, 64);
                    const float hs2_x = __shfl_xor(hs2, 1, 64);
                    const float ue_x  = __shfl_xor(ue, 1, 64);
                    // odd-lane math
                    const float uo  = a0 * a0 - a1 * a1;     // d0^2 - d2^2
                    const float ssq = uo - ue_x;
                    const float qn  = fmaf(s_x, a2, -hs2_x * ssq);
                    // outputs: even {h, s*d1, s*d3}; odd {s*d0, s*d2, qn}
                    o0[r] = vo ? s_x * a0 : hv;
                    o1[r] = vo ? s_x * a1 : s * a1;
                    o2[r] = vo ? qn       : s * a2;
                }
                // write back: frag(nt, ks'=wn), lane' = 16*(2m + (l4>>1)) + l15,
                // e0 = (l4&1)*4  (k = n). Macro expansion keeps every index
                // compile-time constant (rule #20).
                const int wbase = 16 * (2 * m + (l4 >> 1)) + l15;
                const int e0    = (l4 & 1) * 4;
#define WRITE_NT(NTI, OV)                                                      \
                {                                                              \
                    const f16x2 h01 = pkrtz(OV[0], OV[1]);                     \
                    const f16x2 h23 = pkrtz(OV[2], OV[3]);                     \
                    const float q0 = OV[0] - (float)h01[0];                    \
                    const float q1 = OV[1] - (float)h01[1];                    \
                    const float q2 = OV[2] - (float)h23[0];                    \
                    const float q3 = OV[3] - (float)h23[1];                    \
                    const f16x2 g01 = pkrtz(q0, q1);                           \
                    const f16x2 g23 = pkrtz(q2, q3);                           \
                    const int off = (((NTI) * 4 + wn) * 64 + wbase) * 8 + e0;  \
                    *(f16x4*)&sXhi[off] =                                      \
                        __builtin_shufflevector(h01, h23, 0, 1, 2, 3);         \
                    *(f16x4*)&sXlo[off] =                                      \
                        __builtin_shufflevector(g01, g23, 0, 1, 2, 3);         \
                }
                WRITE_NT(0, o0)
                WRITE_NT(1, o1)
                WRITE_NT(2, o2)
#undef WRITE_NT
            }
            __syncthreads();
        } else {
            // last tanh layer + head: res = sum_n W6[n] * q_final[n]  (odd lanes)
            float part = 0.0f;
            #pragma unroll
            for (int m = 0; m < 2; ++m) {
                #pragma unroll
                for (int r = 0; r < 4; ++r) {
                    const int n  = (wn * 2 + m) * 16 + l4 * 4 + r;
                    const float a0 = acc[0][m][r];
                    const float a1 = acc[1][m][r];
                    const float a2 = acc[2][m][r];
                    const float hv  = fast_tanh(a0 + b5[n]);
                    const float s   = 1.0f - hv * hv;
                    const float ue  = a1 * a1 + a2 * a2;
                    const float hs2 = 2.0f * hv * s;
                    const float s_x   = __shfl_xor(s, 1, 64);
                    const float hs2_x = __shfl_xor(hs2, 1, 64);
                    const float ue_x  = __shfl_xor(ue, 1, 64);
                    const float uo  = a0 * a0 - a1 * a1;
                    const float ssq = uo - ue_x;
                    const float qf  = fmaf(s_x, a2, -hs2_x * ssq);
                    part = fmaf(W6[n], qf, part);   // only odd lanes' qf is real
                }
            }
            part += __shfl_xor(part, 16, 64);
            part += __shfl_xor(part, 32, 64);
            if (lane < 16 && (lane & 1)) sRed[wn][lane >> 1] = part;
        }
    }

    __syncthreads();
    if (tid < P) {
        const float rsum = sRed[0][tid] + sRed[1][tid] + sRed[2][tid] + sRed[3][tid];
        const int o = gb + tid;
        if (o < N) out[o] = rsum;
    }
}

extern "C" void kernel_launch(void* const* d_in, const int* in_sizes, int n_in,
                              void* d_out, int out_size, void* d_ws, size_t ws_size,
                              hipStream_t stream) {
    const float* t  = (const float*)d_in[0];
    const float* x  = (const float*)d_in[1];
    const float* y  = (const float*)d_in[2];
    const float* z  = (const float*)d_in[3];
    const float* W0 = (const float*)d_in[4];
    const float* b0 = (const float*)d_in[5];
    const float* W1 = (const float*)d_in[6];
    const float* b1 = (const float*)d_in[7];
    const float* W2 = (const float*)d_in[8];
    const float* b2 = (const float*)d_in[9];
    const float* W3 = (const float*)d_in[10];
    const float* b3 = (const float*)d_in[11];
    const float* W4 = (const float*)d_in[12];
    const float* b4 = (const float*)d_in[13];
    const float* W5 = (const float*)d_in[14];
    const float* b5 = (const float*)d_in[15];
    const float* W6 = (const float*)d_in[16];
    // d_in[17] = b6: unused (drops out of all derivatives)

    const int N = in_sizes[0];
    float* out = (float*)d_out;

    const int use_pre = (ws_size >= WS_NEEDED) ? 1 : 0;
    _Float16* whi = (_Float16*)d_ws;
    _Float16* wlo = whi + WFRAG_HALVES;

    if (use_pre) {
        presplit_w<<<(5 * 8 * 4 * 64) / 256, 256, 0, stream>>>(W1, W2, W3, W4, W5, whi, wlo);
    }
    const int grid = (N + P - 1) / P;
    pinn_mfma12<<<grid, TPB, 0, stream>>>(
        t, x, y, z, W0, b0, W1, b1, W2, b2, W3, b3, W4, b4, W5, b5, W6,
        whi, wlo, use_pre, out, N);
}

// Round 16
// 177.271 us; speedup vs baseline: 1.3135x; 1.2168x over previous
//
#include <hip/hip_runtime.h>
#include <hip/hip_fp16.h>
#include <math.h>

// PhysicsResidual via 2nd-order forward-mode AD, split-fp16 MFMA, operand-swapped.
// State per point: 6 vectors of 128 (h, 4 first derivs, q = signed 2nd-deriv combo).
// Per block: 16 points. Per layer GEMM: A = W (M=128 neurons), B = X^T (N = 6v*16p
// = 96 cols), K = 128. Split-fp16: A*B ~= Wh*Xh + Wh*Xl + Wl*Xh (fp32 MFMA acc).
// Fragment maps (validated R3/R4): arg0 row = lane&15, arg1 col = lane&15,
// k = (lane>>4)*8 + e; D: col = lane&15 (=point), row = (lane>>4)*4 + reg (=neuron).
//
// R16 = R11 verbatim (session best: 176.9us). Design-space map (measured):
//   - prefetch depth: impossible at 3 blocks/CU (R6/R12 spill; R10 occupancy loss)
//   - split-phase pairing (R9): -11%; P=8 (R15): -22%; 2-wave blocks (R7): -27%
//   - bank conflicts: residual 1.73e7 is inherent b128 quarter-wave serialization
//   - MfmaUtil 48 + VALUBusy 46 ~ 94%: both pipes half-fed, barrier-serialized;
//     breaking it needs reg headroom this occupancy point doesn't have.

typedef _Float16 f16x8 __attribute__((ext_vector_type(8)));
typedef _Float16 f16x4 __attribute__((ext_vector_type(4)));
typedef _Float16 f16x2 __attribute__((ext_vector_type(2)));
typedef float    f32x4 __attribute__((ext_vector_type(4)));

constexpr int TPB  = 256;
constexpr int P    = 16;    // points per block
constexpr int H    = 128;
constexpr int NV   = 6;
constexpr int XFRAG_HALVES = NV * 4 * 64 * 8;   // 12288 halves = 24576 B per plane
// pre-split W plane: 5 layers x 8 mt x 4 ks x 64 lanes x 8 halves
constexpr int WFRAG_HALVES = 5 * 8 * 4 * 64 * 8;           // 81920 halves
constexpr size_t WS_NEEDED = 2 * WFRAG_HALVES * sizeof(_Float16); // 327680 B

__device__ __forceinline__ float fast_tanh(float v) {
    float e = __expf(-2.0f * fabsf(v));
    float r = __builtin_amdgcn_rcpf(1.0f + e);
    return copysignf((1.0f - e) * r, v);
}

__device__ __forceinline__ f16x2 pkrtz(float a, float b) {
    return __builtin_bit_cast(f16x2, __builtin_amdgcn_cvt_pkrtz(a, b));
}

// ---------------- pre-split kernel: W1..W5 -> fp16 hi/lo fragments -----------
__global__ __launch_bounds__(256) void presplit_w(
    const float* __restrict__ W1, const float* __restrict__ W2,
    const float* __restrict__ W3, const float* __restrict__ W4,
    const float* __restrict__ W5, _Float16* __restrict__ whi,
    _Float16* __restrict__ wlo)
{
    const int gid = blockIdx.x * 256 + threadIdx.x;   // 0..10239
    const float* Ws[5] = { W1, W2, W3, W4, W5 };
    const int lane = gid & 63;
    const int rest = gid >> 6;        // 0..159
    const int ks   = rest & 3;
    const int mt   = (rest >> 2) & 7;
    const int l    = rest >> 5;       // 0..4
    const int n    = mt * 16 + (lane & 15);
    const int k0   = ks * 32 + (lane >> 4) * 8;
    const float4 u0 = *(const float4*)&Ws[l][n * H + k0];
    const float4 u1 = *(const float4*)&Ws[l][n * H + k0 + 4];
    const float vv[8] = { u0.x, u0.y, u0.z, u0.w, u1.x, u1.y, u1.z, u1.w };
    f16x8 h, o;
    #pragma unroll
    for (int e = 0; e < 8; ++e) {
        _Float16 hh = (_Float16)vv[e];
        h[e] = hh;
        o[e] = (_Float16)(vv[e] - (float)hh);
    }
    *(f16x8*)&whi[gid * 8] = h;
    *(f16x8*)&wlo[gid * 8] = o;
}

// ---------------- main kernel ------------------------------------------------
__global__ __launch_bounds__(TPB, 3) void pinn_mfma8(
    const float* __restrict__ t, const float* __restrict__ x,
    const float* __restrict__ y, const float* __restrict__ z,
    const float* __restrict__ W0, const float* __restrict__ b0,
    const float* __restrict__ W1, const float* __restrict__ b1,
    const float* __restrict__ W2, const float* __restrict__ b2,
    const float* __restrict__ W3, const float* __restrict__ b3,
    const float* __restrict__ W4, const float* __restrict__ b4,
    const float* __restrict__ W5, const float* __restrict__ b5,
    const float* __restrict__ W6,
    const _Float16* __restrict__ whi, const _Float16* __restrict__ wlo,
    int use_pre, float* __restrict__ out, int N)
{
    __shared__ _Float16 sXhi[XFRAG_HALVES];    // 24576 B
    __shared__ _Float16 sXlo[XFRAG_HALVES];    // 24576 B
    __shared__ float    sRed[4][P];            // 256 B -> 49408 B total

    const int tid  = threadIdx.x;
    const int lane = tid & 63;
    const int wn   = tid >> 6;     // wave 0..3: owns neuron tiles mt = wn*2 + nt
    const int l15  = lane & 15;
    const int l4   = lane >> 4;    // 0..3
    const int gb   = blockIdx.x * P;

    // ---------------- layer 0 (input dim 4, analytic tangents) -------------
    {
        const int p0 = tid >> 4;          // 0..15
        const int i0 = tid & 15;          // owns neurons i0*8 .. i0*8+7
        int gp = gb + p0; if (gp >= N) gp = N - 1;
        const float pt0 = t[gp], pt1 = x[gp], pt2 = y[gp], pt3 = z[gp];
        float nv[NV][8];
        #pragma unroll
        for (int j = 0; j < 8; ++j) {
            const int i = i0 * 8 + j;
            const float4 wv = *(const float4*)&W0[i * 4];
            const float zv = fmaf(wv.x, pt0, fmaf(wv.y, pt1, fmaf(wv.z, pt2, fmaf(wv.w, pt3, b0[i]))));
            const float hv = fast_tanh(zv);
            const float s  = 1.0f - hv * hv;
            const float ssq = ((wv.x * wv.x - wv.y * wv.y) - wv.z * wv.z) - wv.w * wv.w;
            nv[0][j] = hv;       nv[1][j] = s * wv.x; nv[2][j] = s * wv.y;
            nv[3][j] = s * wv.z; nv[4][j] = s * wv.w; nv[5][j] = -2.0f * hv * s * ssq;
        }
        // frag-major: element [v][p][k=i0*8+j] -> frag(v, i0>>2), lane p+16*(i0&3), e=j
        #pragma unroll
        for (int v = 0; v < NV; ++v) {
            f16x8 hh, oo;
            #pragma unroll
            for (int j = 0; j < 8; ++j) {
                _Float16 h_ = (_Float16)nv[v][j];
                hh[j] = h_;
                oo[j] = (_Float16)(nv[v][j] - (float)h_);
            }
            const int off = ((v * 4 + (i0 >> 2)) * 64 + p0 + 16 * (i0 & 3)) * 8;
            *(f16x8*)&sXhi[off] = hh;
            *(f16x8*)&sXlo[off] = oo;
        }
    }
    __syncthreads();

    for (int l = 0; l < 5; ++l) {
        f32x4 acc[NV][2];
        #pragma unroll
        for (int v = 0; v < NV; ++v)
            #pragma unroll
            for (int nt = 0; nt < 2; ++nt) acc[v][nt] = (f32x4){0.f, 0.f, 0.f, 0.f};

        const float* __restrict__ Wc =
            (l == 0) ? W1 : (l == 1) ? W2 : (l == 2) ? W3 : (l == 3) ? W4 : W5;

        #pragma unroll
        for (int ks = 0; ks < 4; ++ks) {
            // A frags (W hi/lo) for this ks only (NO cross-ks hoist: R6 spilled)
            f16x8 ah[2], al[2];
            if (use_pre) {
                #pragma unroll
                for (int nt = 0; nt < 2; ++nt) {
                    const int f = ((l * 8 + (wn * 2 + nt)) * 4 + ks) * 64 + lane;
                    ah[nt] = *(const f16x8*)&whi[f * 8];
                    al[nt] = *(const f16x8*)&wlo[f * 8];
                }
            } else {
                #pragma unroll
                for (int nt = 0; nt < 2; ++nt) {
                    const int n  = (wn * 2 + nt) * 16 + l15;
                    const int k0 = ks * 32 + l4 * 8;
                    const float4 u0 = *(const float4*)&Wc[n * H + k0];
                    const float4 u1 = *(const float4*)&Wc[n * H + k0 + 4];
                    const float vv[8] = { u0.x, u0.y, u0.z, u0.w, u1.x, u1.y, u1.z, u1.w };
                    #pragma unroll
                    for (int e = 0; e < 8; ++e) {
                        _Float16 h_ = (_Float16)vv[e];
                        ah[nt][e] = h_;
                        al[nt][e] = (_Float16)(vv[e] - (float)h_);
                    }
                }
            }
            // B frags: lane-contiguous 16B reads (zero-conflict by construction)
            f16x8 xh[NV], xl[NV];
            #pragma unroll
            for (int v = 0; v < NV; ++v) {
                const int base = ((v * 4 + ks) * 64 + lane) * 8;
                xh[v] = *(const f16x8*)&sXhi[base];
                xl[v] = *(const f16x8*)&sXlo[base];
            }
            __builtin_amdgcn_s_setprio(1);
            #pragma unroll
            for (int v = 0; v < NV; ++v)
                #pragma unroll
                for (int nt = 0; nt < 2; ++nt)
                    acc[v][nt] = __builtin_amdgcn_mfma_f32_16x16x32_f16(ah[nt], xh[v], acc[v][nt], 0, 0, 0);
            #pragma unroll
            for (int v = 0; v < NV; ++v)
                #pragma unroll
                for (int nt = 0; nt < 2; ++nt)
                    acc[v][nt] = __builtin_amdgcn_mfma_f32_16x16x32_f16(ah[nt], xl[v], acc[v][nt], 0, 0, 0);
            #pragma unroll
            for (int v = 0; v < NV; ++v)
                #pragma unroll
                for (int nt = 0; nt < 2; ++nt)
                    acc[v][nt] = __builtin_amdgcn_mfma_f32_16x16x32_f16(al[nt], xh[v], acc[v][nt], 0, 0, 0);
            __builtin_amdgcn_s_setprio(0);
        }
        __syncthreads();   // all GEMM reads of sX complete before overwrite

        if (l < 4) {
            // D: col = point = l15, row = neuron n = (wn*2+nt)*16 + l4*4 + r
            const float* __restrict__ bc =
                (l == 0) ? b1 : (l == 1) ? b2 : (l == 2) ? b3 : b4;
            #pragma unroll
            for (int nt = 0; nt < 2; ++nt) {
                const int n0  = (wn * 2 + nt) * 16 + l4 * 4;
                const int ksp = n0 >> 5;            // next-layer frag ks
                const int l4p = (n0 & 31) >> 3;     // k-subgroup
                const int e0  = n0 & 7;             // 0 or 4
                const float4 b4v = *(const float4*)&bc[n0];
                const float bb[4] = { b4v.x, b4v.y, b4v.z, b4v.w };
                float nv[NV][4];
                #pragma unroll
                for (int r = 0; r < 4; ++r) {
                    const float zv = acc[0][nt][r] + bb[r];
                    const float hv = fast_tanh(zv);
                    const float s  = 1.0f - hv * hv;
                    const float d0 = acc[1][nt][r], d1 = acc[2][nt][r];
                    const float d2 = acc[3][nt][r], d3 = acc[4][nt][r];
                    const float ssq = ((d0 * d0 - d1 * d1) - d2 * d2) - d3 * d3;
                    const float qn  = fmaf(s, acc[5][nt][r], -2.0f * hv * s * ssq);
                    nv[0][r] = hv;     nv[1][r] = s * d0; nv[2][r] = s * d1;
                    nv[3][r] = s * d2; nv[4][r] = s * d3; nv[5][r] = qn;
                }
                #pragma unroll
                for (int v = 0; v < NV; ++v) {
                    const f16x2 h01 = pkrtz(nv[v][0], nv[v][1]);
                    const f16x2 h23 = pkrtz(nv[v][2], nv[v][3]);
                    const float o0 = nv[v][0] - (float)h01[0];
                    const float o1 = nv[v][1] - (float)h01[1];
                    const float o2 = nv[v][2] - (float)h23[0];
                    const float o3 = nv[v][3] - (float)h23[1];
                    const f16x2 o01 = pkrtz(o0, o1);
                    const f16x2 o23 = pkrtz(o2, o3);
                    // frag-major: [v][p=l15][k=n0+r] -> frag(v,ksp), lane l15+16*l4p, e=e0+r
                    const int off = ((v * 4 + ksp) * 64 + l15 + 16 * l4p) * 8 + e0;
                    *(f16x4*)&sXhi[off] = __builtin_shufflevector(h01, h23, 0, 1, 2, 3);
                    *(f16x4*)&sXlo[off] = __builtin_shufflevector(o01, o23, 0, 1, 2, 3);
                }
            }
            __syncthreads();
        } else {
            // last tanh layer + linear head fused: res = W6 . q_final
            float part = 0.0f;
            #pragma unroll
            for (int nt = 0; nt < 2; ++nt) {
                const int n0 = (wn * 2 + nt) * 16 + l4 * 4;
                const float4 b4v = *(const float4*)&b5[n0];
                const float4 w6v = *(const float4*)&W6[n0];
                const float bb[4] = { b4v.x, b4v.y, b4v.z, b4v.w };
                const float ww[4] = { w6v.x, w6v.y, w6v.z, w6v.w };
                #pragma unroll
                for (int r = 0; r < 4; ++r) {
                    const float zv = acc[0][nt][r] + bb[r];
                    const float hv = fast_tanh(zv);
                    const float s  = 1.0f - hv * hv;
                    const float d0 = acc[1][nt][r], d1 = acc[2][nt][r];
                    const float d2 = acc[3][nt][r], d3 = acc[4][nt][r];
                    const float ssq = ((d0 * d0 - d1 * d1) - d2 * d2) - d3 * d3;
                    const float qf  = fmaf(s, acc[5][nt][r], -2.0f * hv * s * ssq);
                    part = fmaf(ww[r], qf, part);
                }
            }
            // lanes {l15, l15+16, l15+32, l15+48}: different neurons, same point
            part += __shfl_xor(part, 16, 64);
            part += __shfl_xor(part, 32, 64);
            if (lane < 16) sRed[wn][lane] = part;
        }
    }

    __syncthreads();
    if (tid < P) {
        const float rsum = sRed[0][tid] + sRed[1][tid] + sRed[2][tid] + sRed[3][tid];
        const int o = gb + tid;
        if (o < N) out[o] = rsum;
    }
}

extern "C" void kernel_launch(void* const* d_in, const int* in_sizes, int n_in,
                              void* d_out, int out_size, void* d_ws, size_t ws_size,
                              hipStream_t stream) {
    const float* t  = (const float*)d_in[0];
    const float* x  = (const float*)d_in[1];
    const float* y  = (const float*)d_in[2];
    const float* z  = (const float*)d_in[3];
    const float* W0 = (const float*)d_in[4];
    const float* b0 = (const float*)d_in[5];
    const float* W1 = (const float*)d_in[6];
    const float* b1 = (const float*)d_in[7];
    const float* W2 = (const float*)d_in[8];
    const float* b2 = (const float*)d_in[9];
    const float* W3 = (const float*)d_in[10];
    const float* b3 = (const float*)d_in[11];
    const float* W4 = (const float*)d_in[12];
    const float* b4 = (const float*)d_in[13];
    const float* W5 = (const float*)d_in[14];
    const float* b5 = (const float*)d_in[15];
    const float* W6 = (const float*)d_in[16];
    // d_in[17] = b6: unused (drops out of all derivatives)

    const int N = in_sizes[0];
    float* out = (float*)d_out;

    const int use_pre = (ws_size >= WS_NEEDED) ? 1 : 0;
    _Float16* whi = (_Float16*)d_ws;
    _Float16* wlo = whi + WFRAG_HALVES;

    if (use_pre) {
        presplit_w<<<(5 * 8 * 4 * 64) / 256, 256, 0, stream>>>(W1, W2, W3, W4, W5, whi, wlo);
    }
    const int grid = (N + P - 1) / P;
    pinn_mfma8<<<grid, TPB, 0, stream>>>(
        t, x, y, z, W0, b0, W1, b1, W2, b2, W3, b3, W4, b4, W5, b5, W6,
        whi, wlo, use_pre, out, N);
}